// Round 8
// baseline (590.793 us; speedup 1.0000x reference)
//
#include <hip/hip_runtime.h>

#define BB 16
#define HH 128
#define WW 128
#define FF 64
#define NPIX (BB*HH*WW)   // 262144

typedef short bf16x8 __attribute__((ext_vector_type(8)));
typedef float f32x4 __attribute__((ext_vector_type(4)));

__device__ __forceinline__ float bf2f(unsigned int u){ return __uint_as_float(u<<16); }
__device__ __forceinline__ unsigned short f2bf(float f){
  unsigned u = __float_as_uint(f);
  u += 0x7fffu + ((u>>16)&1u);           // RNE
  return (unsigned short)(u>>16);
}
__device__ __forceinline__ float hsig(float x){ return fminf(fmaxf(fmaf(0.2f,x,0.5f),0.f),1.f); }
// NaN-safe fast tanh: e->inf gives 1, e->0 gives -1
__device__ __forceinline__ float tanh_fast(float x){
  float e = __expf(2.f*x);
  return 1.f - 2.f/(e + 1.f);
}
__device__ __forceinline__ void gload_lds16(const void* g, void* l){
  __builtin_amdgcn_global_load_lds(
      (const __attribute__((address_space(1))) unsigned int*)g,
      (__attribute__((address_space(3))) unsigned int*)l, 16, 0, 0);
}

// ---------- merged prep: halo pads + X interleave + W relayout ----------
__global__ __launch_bounds__(256) void prep_all(
    const float* __restrict__ in, const float* __restrict__ h0,
    const float* __restrict__ kern, const float* __restrict__ rkern,
    unsigned short* __restrict__ Xp, unsigned short* __restrict__ Wg){
  const int blk = blockIdx.x;
  const int t = threadIdx.x;
  if (blk < 33){
    // zero halo pads of Xbpad[16][130][130][128]
    int i = blk*256 + t;
    if (i >= 16*516) return;
    int b = i / 516, r = i % 516;
    int y, x;
    if (r < 130){ y = 0; x = r; }
    else if (r < 260){ y = 129; x = r-130; }
    else if (r < 388){ y = r-260+1; x = 0; }
    else { y = r-388+1; x = 129; }
    unsigned short* p = Xp + (((size_t)(b*130 + y)*130) + x)*128;
    uint4 z = {0u,0u,0u,0u};
    #pragma unroll
    for (int c=0;c<16;++c) ((uint4*)p)[c] = z;
  } else if (blk < 33 + 16384){
    // prep X: interleave inputs(64ch)+h0(64ch) bf16 into padded interior
    int gi = (blk-33)*256 + t;
    int pix = gi >> 4;
    int ch8 = (gi & 15) * 8;
    const float* src = (ch8 < 64) ? (in + (size_t)pix*64 + ch8)
                                  : (h0 + (size_t)pix*64 + (ch8-64));
    float4 v0 = *(const float4*)src;
    float4 v1 = *(const float4*)(src+4);
    uint4 o;
    o.x = (unsigned)f2bf(v0.x) | ((unsigned)f2bf(v0.y)<<16);
    o.y = (unsigned)f2bf(v0.z) | ((unsigned)f2bf(v0.w)<<16);
    o.z = (unsigned)f2bf(v1.x) | ((unsigned)f2bf(v1.y)<<16);
    o.w = (unsigned)f2bf(v1.z) | ((unsigned)f2bf(v1.w)<<16);
    int b = pix >> 14, y = (pix >> 7) & 127, x = pix & 127;
    *(uint4*)(Xp + (((size_t)(b*130 + y+1)*130) + (x+1))*128 + ch8) = o;
  } else {
    // prep W: Wg[n][tap*128 + c] bf16, K-contiguous per n
    int k = blk - (33 + 16384);    // 0..1151
    int n = t;                     // 0..255
    int tap = k >> 7, c = k & 127;
    float v = (c < 64) ? kern[((size_t)(tap*64 + c))*256 + n]
                       : rkern[((size_t)(tap*64 + (c-64)))*256 + n];
    Wg[(size_t)n*1152 + k] = f2bf(v);
  }
}

// ---------- gates: implicit-GEMM conv (M=128px row, N=256 gates, K=1152) + LSTM ----------
// FROZEN (R5 form, measured 235-237 us). Post-R5 model: at the forced
// 2-waves/SIMD operating point the wall ~= serialized pipe demands
// (MFMA 74 + LDS 61 + VALU 47 + L2 34 us); schedule variants all null.
__global__ __launch_bounds__(256, 2) void gates_kernel(
    const unsigned short* __restrict__ Xp,
    const unsigned short* __restrict__ Wg,
    const float* __restrict__ bias,
    const float* __restrict__ c0,
    float* __restrict__ c_out,
    unsigned short* __restrict__ h_bf){
  __shared__ unsigned short As[2][130*128];  // 2 x 33,280 B
  const int gid = blockIdx.x;
  const int swz = (gid & 7)*256 + (gid >> 3);
  const int b  = swz >> 7;
  const int y  = swz & 127;
  const int tid = threadIdx.x;
  const int l = tid & 63;
  const int wid = tid >> 6;                 // 0..3 (n-partition)
  const int l15 = l & 15, l4 = l >> 4;
  const int n0 = wid*16 + l15;              // channel-within-gate this lane owns

  const unsigned short* brow[4];
  #pragma unroll
  for (int g=0; g<4; ++g) brow[g] = Wg + (size_t)(g*64 + n0)*1152 + l4*8;

  f32x4 acc[8][4];                          // [m-frag][gate]
  #pragma unroll
  for (int mf=0;mf<8;++mf)
    #pragma unroll
    for (int g=0;g<4;++g) acc[mf][g] = (f32x4){0.f,0.f,0.f,0.f};

  auto stage = [&](int buf, int dyi){       // exactly 9 vmem insts per wave
    const unsigned short* gbase = Xp + ((size_t)((b*130 + y + dyi)*130))*128;
    unsigned short* lbase = &As[buf][0];
    #pragma unroll
    for (int it=0; it<8; ++it){             // 130*16 = 2080 chunks of 16B
      int q = it*256 + tid;
      int px = q >> 4, c = q & 15;
      int cs = c ^ (px & 7);
      gload_lds16(gbase + (size_t)px*128 + cs*8, lbase + (size_t)q*8);
    }
    if (l < 8){                             // per-wave tail: 8 chunks each
      int q = 2048 + wid*8 + l;
      int px = q >> 4, c = q & 15;
      int cs = c ^ (px & 7);
      gload_lds16(gbase + (size_t)px*128 + cs*8, lbase + (size_t)q*8);
    }
  };

  stage(0, 0);
  for (int dyi = 0; dyi < 3; ++dyi){
    if (dyi < 2){
      stage((dyi+1)&1, dyi+1);              // prefetch next strip (other buf)
      asm volatile("s_waitcnt vmcnt(9)" ::: "memory");   // current strip done;
    } else {                                             // prefetch in flight
      asm volatile("s_waitcnt vmcnt(0)" ::: "memory");
    }
    __builtin_amdgcn_sched_barrier(0);
    __builtin_amdgcn_s_barrier();           // all waves' strip data visible
    __builtin_amdgcn_sched_barrier(0);
    const unsigned short* asb = &As[dyi&1][0];
    #pragma unroll
    for (int dxi = 0; dxi < 3; ++dxi){
      const int tap = dyi*3 + dxi;
      #pragma unroll
      for (int ksc = 0; ksc < 2; ++ksc){    // two half-ksteps
        bf16x8 bfr[4][2];                   // 32 VGPR, serves 64 MFMAs
        #pragma unroll
        for (int g=0; g<4; ++g)
          #pragma unroll
          for (int k2=0; k2<2; ++k2)
            bfr[g][k2] = *(const bf16x8*)(brow[g] + tap*128 + (ksc*2+k2)*32);
        #pragma unroll
        for (int k2=0; k2<2; ++k2){
          const int cd = (ksc*2+k2)*4 + l4;
          #pragma unroll
          for (int mf=0; mf<8; ++mf){
            const int px = mf*16 + l15 + dxi;   // 0..129 in strip
            bf16x8 a = *(const bf16x8*)(asb + (size_t)px*128 + ((cd ^ (px & 7))*8));
            #pragma unroll
            for (int g=0;g<4;++g)
              acc[mf][g] = __builtin_amdgcn_mfma_f32_16x16x32_bf16(a, bfr[g][k2], acc[mf][g], 0,0,0);
          }
        }
      }
    }
    __builtin_amdgcn_sched_barrier(0);
    __builtin_amdgcn_s_barrier();           // reads done before buf reuse
    __builtin_amdgcn_sched_barrier(0);
  }
  // epilogue: all 4 gates of channel n0 live in the same lane/reg slot
  const float b0 = bias[n0], b1 = bias[64+n0], b2 = bias[128+n0], b3 = bias[192+n0];
  const size_t prow = (size_t)(b*128 + y)*128;
  #pragma unroll
  for (int mf=0;mf<8;++mf){
    #pragma unroll
    for (int r=0;r<4;++r){
      const int x = mf*16 + l4*4 + r;       // C/D row = (lane>>4)*4 + reg
      const size_t p = prow + x;
      const float zi_ = acc[mf][0][r] + b0;
      const float zf_ = acc[mf][1][r] + b1;
      const float zc_ = acc[mf][2][r] + b2;
      const float zo_ = acc[mf][3][r] + b3;
      const float iv = hsig(zi_), fv = hsig(zf_), ov = hsig(zo_);
      const float cv = fv*c0[p*64 + n0] + iv*tanh_fast(zc_);
      const float hv = ov*tanh_fast(cv);
      c_out[p*64 + n0] = cv;
      h_bf[p*64 + n0] = f2bf(hv);
    }
  }
}

// ---------- attention v4: qkv folded in, LDS-staged K/V ----------
// R8: the separate qkv kernel (100 MB re-read of h_bf/m0 + 5 MB q/k/v
// round-trip + one launch boundary) is folded into attn. 64 blocks
// (16b x 2type x 2 row-halves): phase A computes this (b,type)'s K,V
// columns from h_bf/m0 straight into the padded LDS tiles (same fma order
// as the old qkv -> same numerics); phase B computes Q rows per pass and
// runs the proven R7 dot/softmax/PV. 2x redundant h/m0 reads (row-halves)
// is the price; K/V compute is VALU-cheap.
__global__ __launch_bounds__(256) void attn_kernel(
    const unsigned short* __restrict__ h_bf, const float* __restrict__ m0,
    const float* __restrict__ sak,
    float* __restrict__ z_h, float* __restrict__ z_m){
  __shared__ float Kl[128][132];
  __shared__ float Vl[128][132];
  __shared__ float q2[8][132];
  __shared__ float al[8][132];
  __shared__ float wS[320];
  const int bid = blockIdx.x;              // 16b x 2type x 2rh
  const int b = bid >> 2;
  const int type = (bid >> 1) & 1;
  const int rh = bid & 1;                  // rows rh*64 .. rh*64+63
  const int t = threadIdx.x;
  const int jq = t & 31;                   // col quad: j = jq*4
  const int r8 = t >> 5;                   // row within pass: 0..7
  for (int i = t; i < 320; i += 256) wS[i] = sak[i];
  __syncthreads();
  const unsigned short* hB = h_bf + (size_t)b*16384*64;
  const float* mB = m0 + (size_t)b*16384*64;
  float* Z = (type ? z_m : z_h) + (size_t)b*16384;

  // ---- phase A: K,V columns for all 16384 px of this (b,type) ----
  for (int base = 0; base < 16384; base += 256){
    const int p = base + t;
    float kv = 0.f, vv = 0.f;
    if (type == 0){
      const unsigned short* hp = hB + (size_t)p*64;
      #pragma unroll
      for (int ch = 0; ch < 64; ch += 8){
        uint4 hu = *(const uint4*)(hp + ch);
        float hv[8] = { bf2f(hu.x&0xffffu), bf2f(hu.x>>16), bf2f(hu.y&0xffffu), bf2f(hu.y>>16),
                        bf2f(hu.z&0xffffu), bf2f(hu.z>>16), bf2f(hu.w&0xffffu), bf2f(hu.w>>16) };
        #pragma unroll
        for (int jj=0;jj<8;++jj){
          kv = fmaf(hv[jj], wS[(ch+jj)*5 + 1], kv);   // k_h
          vv = fmaf(hv[jj], wS[(ch+jj)*5 + 0], vv);   // v_h
        }
      }
    } else {
      const float* mp = mB + (size_t)p*64;
      #pragma unroll
      for (int ch = 0; ch < 64; ch += 8){
        float4 ma = *(const float4*)(mp + ch);
        float4 mb2 = *(const float4*)(mp + ch + 4);
        float mv[8] = { ma.x,ma.y,ma.z,ma.w, mb2.x,mb2.y,mb2.z,mb2.w };
        #pragma unroll
        for (int jj=0;jj<8;++jj){
          kv = fmaf(mv[jj], wS[(ch+jj)*5 + 3], kv);   // k_m
          vv = fmaf(mv[jj], wS[(ch+jj)*5 + 4], vv);   // v_m
        }
      }
    }
    Kl[p>>7][p&127] = kv;
    Vl[p>>7][p&127] = vv;
  }

  // ---- phase B: 8 passes x 8 rows ----
  for (int pass = 0; pass < 8; ++pass){
    __syncthreads();                       // K/V staged / prev pass done
    for (int idx = t; idx < 1024; idx += 256){
      const int rr = idx >> 7, j = idx & 127;
      const int p = (rh*64 + pass*8 + rr)*128 + j;
      const unsigned short* hp = hB + (size_t)p*64;
      float qv = 0.f;
      #pragma unroll
      for (int ch = 0; ch < 64; ch += 8){
        uint4 hu = *(const uint4*)(hp + ch);
        float hv[8] = { bf2f(hu.x&0xffffu), bf2f(hu.x>>16), bf2f(hu.y&0xffffu), bf2f(hu.y>>16),
                        bf2f(hu.z&0xffffu), bf2f(hu.z>>16), bf2f(hu.w&0xffffu), bf2f(hu.w>>16) };
        #pragma unroll
        for (int jj=0;jj<8;++jj)
          qv = fmaf(hv[jj], wS[(ch+jj)*5 + 2], qv);   // q_h
      }
      q2[rr][j] = qv;
    }
    __syncthreads();
    const int i = rh*64 + pass*8 + r8;
    float s0=0.f,s1=0.f,s2=0.f,s3=0.f;
    #pragma unroll 8
    for (int w=0; w<128; ++w){
      const float qv = q2[r8][w];
      const float4 kv = *(const float4*)&Kl[w][jq*4];
      s0 = fmaf(qv, kv.x, s0); s1 = fmaf(qv, kv.y, s1);
      s2 = fmaf(qv, kv.z, s2); s3 = fmaf(qv, kv.w, s3);
    }
    float mx = fmaxf(fmaxf(s0,s1), fmaxf(s2,s3));
    #pragma unroll
    for (int o=1;o<32;o<<=1) mx = fmaxf(mx, __shfl_xor(mx, o));
    const float p0 = __expf(s0-mx), p1 = __expf(s1-mx);
    const float p2 = __expf(s2-mx), p3 = __expf(s3-mx);
    float sm = (p0+p1)+(p2+p3);
    #pragma unroll
    for (int o=1;o<32;o<<=1) sm += __shfl_xor(sm, o);
    const float inv = 1.f/sm;
    *(float4*)&al[r8][jq*4] = make_float4(p0*inv, p1*inv, p2*inv, p3*inv);
    __syncthreads();
    float z0=0.f,z1=0.f,z2=0.f,z3=0.f;
    #pragma unroll 8
    for (int w=0; w<128; ++w){
      const float av = al[r8][w];
      const float4 vv = *(const float4*)&Vl[w][jq*4];
      z0 = fmaf(av, vv.x, z0); z1 = fmaf(av, vv.y, z1);
      z2 = fmaf(av, vv.z, z2); z3 = fmaf(av, vv.w, z3);
    }
    *(float4*)(Z + (size_t)i*128 + jq*4) = make_float4(z0,z1,z2,z3);
  }
}

// ---------- FUSED zconv + depthwise/SAM final ----------
__global__ __launch_bounds__(512) void final_fused(
    const float* __restrict__ z_h, const float* __restrict__ z_m,
    const float* __restrict__ kz,
    const unsigned short* __restrict__ h_bf,
    const float* __restrict__ m0, const float* __restrict__ dwk,
    const float* __restrict__ sab,
    float* __restrict__ hhat, float* __restrict__ m_t){
  __shared__ unsigned short zi[4][128][64];   // 64 KB
  const int f = threadIdx.x & 63;
  const int g = threadIdx.x >> 6;             // 0..7
  const int blk = blockIdx.x;                 // 16 b x 64 ytiles (2 rows)
  const int b = blk >> 6;
  const int y0 = (blk & 63) * 2;

  // ---- phase 1: zi rows y0-1..y0+2 -> LDS ----
  {
    const int ry = g >> 1;                    // 0..3 (which zi row)
    const int xh = g & 1;                     // x half
    const int yy = y0 - 1 + ry;
    const int x0 = xh * 64;
    if ((unsigned)yy >= 128u){
      for (int i=0;i<64;++i) zi[ry][x0+i][f] = 0;
    } else {
      float w0[9], w1[9];
      #pragma unroll
      for (int tap=0; tap<9; ++tap){
        w0[tap] = kz[tap*128 + f];
        w1[tap] = kz[tap*128 + 64 + f];
      }
      const float* zhr = z_h + (size_t)(b*128 + yy)*128;
      const float* zmr = z_m + (size_t)(b*128 + yy)*128;
      const bool ym = (yy > 0), yp = (yy < 127);
      float az[3][3], am[3][3];               // [col: x-1,x,x+1][row dy 0..2]
      auto ldc = [&](int x, float (&Z)[3], float (&M)[3]){
        if ((unsigned)x < 128u){
          Z[0] = ym ? zhr[x-128] : 0.f;  M[0] = ym ? zmr[x-128] : 0.f;
          Z[1] = zhr[x];                 M[1] = zmr[x];
          Z[2] = yp ? zhr[x+128] : 0.f;  M[2] = yp ? zmr[x+128] : 0.f;
        } else { Z[0]=Z[1]=Z[2]=0.f; M[0]=M[1]=M[2]=0.f; }
      };
      ldc(x0-1, az[0], am[0]);
      ldc(x0,   az[1], am[1]);
      for (int i=0; i<64; ++i){
        const int x = x0 + i;
        ldc(x+1, az[2], am[2]);
        float acc = 0.f;
        #pragma unroll
        for (int tap=0; tap<9; ++tap){
          const int dy = tap/3, dx = tap%3;
          acc = fmaf(az[dx][dy], w0[tap], acc);
          acc = fmaf(am[dx][dy], w1[tap], acc);
        }
        zi[ry][x][f] = f2bf(acc);
        #pragma unroll
        for (int k=0;k<3;++k){
          az[0][k]=az[1][k]; az[1][k]=az[2][k];
          am[0][k]=am[1][k]; am[1][k]=am[2][k];
        }
      }
    }
  }
  __syncthreads();

  // ---- phase 2: depthwise convs + SAM gates + elementwise ----
  const int r2 = g >> 2;                      // output row within tile (0/1)
  const int xq = g & 3;                       // x quarter
  const int y = y0 + r2;
  const size_t rb = (size_t)(b*128 + y)*128;
  float wv[9][6];
  #pragma unroll
  for (int tap=0;tap<9;++tap)
    #pragma unroll
    for (int jj=0;jj<6;++jj) wv[tap][jj] = dwk[(tap*64 + f)*6 + jj];
  const float bi = sab[f], bg = sab[64+f], bo = sab[128+f];
  const bool ym = (y > 0), yp = (y < 127);
  float vz[3][3], vh[3][3];                   // [col: x-1,x,x+1][row dy 0..2]
  auto ldc2 = [&](int x, float (&Z)[3], float (&H)[3]){
    if ((unsigned)x < 128u){
      const size_t base = (rb + x)*64 + f;
      H[0] = ym ? bf2f(h_bf[base - 8192]) : 0.f;
      H[1] = bf2f(h_bf[base]);
      H[2] = yp ? bf2f(h_bf[base + 8192]) : 0.f;
      Z[0] = bf2f(zi[r2  ][x][f]);            // zi row y-1 (zero-filled if OOR)
      Z[1] = bf2f(zi[r2+1][x][f]);            // zi row y
      Z[2] = bf2f(zi[r2+2][x][f]);            // zi row y+1
    } else { Z[0]=Z[1]=Z[2]=0.f; H[0]=H[1]=H[2]=0.f; }
  };
  const int x0 = xq*32;
  ldc2(x0-1, vz[0], vh[0]);
  ldc2(x0,   vz[1], vh[1]);
  for (int i=0; i<32; ++i){
    const int x = x0 + i;
    ldc2(x+1, vz[2], vh[2]);
    float si=0.f, sg=0.f, so=0.f;
    #pragma unroll
    for (int tap=0;tap<9;++tap){
      const int dy = tap/3, dx = tap%3;
      const float zv = vz[dx][dy], hv = vh[dx][dy];
      si = fmaf(zv, wv[tap][0], si); si = fmaf(hv, wv[tap][1], si);
      sg = fmaf(zv, wv[tap][2], sg); sg = fmaf(hv, wv[tap][3], sg);
      so = fmaf(zv, wv[tap][4], so); so = fmaf(hv, wv[tap][5], so);
    }
    const size_t p = rb + x;
    const float i2 = 1.f/(1.f+__expf(-(si+bi)));
    const float gg = tanh_fast(sg+bg);
    const float o2 = 1.f/(1.f+__expf(-(so+bo)));
    const float mv = m0[p*64+f];
    const float mt = (1.f-i2)*mv + i2*gg;
    hhat[p*64+f] = mt*o2;
    m_t[p*64+f]  = mt;
    #pragma unroll
    for (int k=0;k<3;++k){
      vz[0][k]=vz[1][k]; vz[1][k]=vz[2][k];
      vh[0][k]=vh[1][k]; vh[1][k]=vh[2][k];
    }
  }
}

extern "C" void kernel_launch(void* const* d_in, const int* in_sizes, int n_in,
                              void* d_out, int out_size, void* d_ws, size_t ws_size,
                              hipStream_t stream){
  const float* inputs = (const float*)d_in[0];
  const float* h0p    = (const float*)d_in[1];
  const float* c0p    = (const float*)d_in[2];
  const float* m0p    = (const float*)d_in[3];
  const float* kern   = (const float*)d_in[4];
  const float* rkern  = (const float*)d_in[5];
  const float* biasp  = (const float*)d_in[6];
  const float* sakp   = (const float*)d_in[7];
  const float* kzp    = (const float*)d_in[8];
  const float* dwkp   = (const float*)d_in[9];
  const float* sabp   = (const float*)d_in[10];
  float* out = (float*)d_out;
  char* ws = (char*)d_ws;

  constexpr size_t SZ_XP  = (size_t)16*130*130*128*2;  // 69,222,400
  constexpr size_t SZ_WG  = (size_t)256*1152*2;        //    589,824
  constexpr size_t SZ_HBF = (size_t)NPIX*64*2;         // 33,554,432
  constexpr size_t SZA    = (size_t)NPIX*4;            //  1,048,576
  constexpr size_t OFF_XP  = 0;
  constexpr size_t OFF_WG  = OFF_XP + SZ_XP;
  constexpr size_t OFF_HBF = OFF_WG + SZ_WG;
  constexpr size_t OFF_ZH  = OFF_HBF + SZ_HBF;
  constexpr size_t OFF_ZM  = OFF_ZH + SZA;

  unsigned short* Xp  = (unsigned short*)(ws + OFF_XP);
  unsigned short* Wg  = (unsigned short*)(ws + OFF_WG);
  unsigned short* Hbf = (unsigned short*)(ws + OFF_HBF);
  float* Zh = (float*)(ws + OFF_ZH);
  float* Zm = (float*)(ws + OFF_ZM);

  prep_all<<<33 + 16384 + 1152, 256, 0, stream>>>(inputs, h0p, kern, rkern, Xp, Wg);
  gates_kernel<<<2048, 256, 0, stream>>>(Xp, Wg, biasp, c0p,
                                         out + (size_t)NPIX*64, Hbf);
  attn_kernel<<<64, 256, 0, stream>>>(Hbf, m0p, sakp, Zh, Zm);
  final_fused<<<1024, 512, 0, stream>>>(Zh, Zm, kzp, Hbf, m0p, dwkp, sabp,
                                        out, out + 2*(size_t)NPIX*64);
}

// Round 9
// 400.424 us; speedup vs baseline: 1.4754x; 1.4754x over previous
//
#include <hip/hip_runtime.h>

#define BB 16
#define HH 128
#define WW 128
#define FF 64
#define NPIX (BB*HH*WW)   // 262144

typedef short bf16x8 __attribute__((ext_vector_type(8)));
typedef float f32x4 __attribute__((ext_vector_type(4)));

__device__ __forceinline__ float bf2f(unsigned int u){ return __uint_as_float(u<<16); }
__device__ __forceinline__ unsigned short f2bf(float f){
  unsigned u = __float_as_uint(f);
  u += 0x7fffu + ((u>>16)&1u);           // RNE
  return (unsigned short)(u>>16);
}
__device__ __forceinline__ float hsig(float x){ return fminf(fmaxf(fmaf(0.2f,x,0.5f),0.f),1.f); }
// NaN-safe fast tanh: e->inf gives 1, e->0 gives -1
__device__ __forceinline__ float tanh_fast(float x){
  float e = __expf(2.f*x);
  return 1.f - 2.f/(e + 1.f);
}
__device__ __forceinline__ void gload_lds16(const void* g, void* l){
  __builtin_amdgcn_global_load_lds(
      (const __attribute__((address_space(1))) unsigned int*)g,
      (__attribute__((address_space(3))) unsigned int*)l, 16, 0, 0);
}

// ---------- merged prep: halo pads + X interleave + W relayout ----------
__global__ __launch_bounds__(256) void prep_all(
    const float* __restrict__ in, const float* __restrict__ h0,
    const float* __restrict__ kern, const float* __restrict__ rkern,
    unsigned short* __restrict__ Xp, unsigned short* __restrict__ Wg){
  const int blk = blockIdx.x;
  const int t = threadIdx.x;
  if (blk < 33){
    // zero halo pads of Xbpad[16][130][130][128]
    int i = blk*256 + t;
    if (i >= 16*516) return;
    int b = i / 516, r = i % 516;
    int y, x;
    if (r < 130){ y = 0; x = r; }
    else if (r < 260){ y = 129; x = r-130; }
    else if (r < 388){ y = r-260+1; x = 0; }
    else { y = r-388+1; x = 129; }
    unsigned short* p = Xp + (((size_t)(b*130 + y)*130) + x)*128;
    uint4 z = {0u,0u,0u,0u};
    #pragma unroll
    for (int c=0;c<16;++c) ((uint4*)p)[c] = z;
  } else if (blk < 33 + 16384){
    // prep X: interleave inputs(64ch)+h0(64ch) bf16 into padded interior
    int gi = (blk-33)*256 + t;
    int pix = gi >> 4;
    int ch8 = (gi & 15) * 8;
    const float* src = (ch8 < 64) ? (in + (size_t)pix*64 + ch8)
                                  : (h0 + (size_t)pix*64 + (ch8-64));
    float4 v0 = *(const float4*)src;
    float4 v1 = *(const float4*)(src+4);
    uint4 o;
    o.x = (unsigned)f2bf(v0.x) | ((unsigned)f2bf(v0.y)<<16);
    o.y = (unsigned)f2bf(v0.z) | ((unsigned)f2bf(v0.w)<<16);
    o.z = (unsigned)f2bf(v1.x) | ((unsigned)f2bf(v1.y)<<16);
    o.w = (unsigned)f2bf(v1.z) | ((unsigned)f2bf(v1.w)<<16);
    int b = pix >> 14, y = (pix >> 7) & 127, x = pix & 127;
    *(uint4*)(Xp + (((size_t)(b*130 + y+1)*130) + (x+1))*128 + ch8) = o;
  } else {
    // prep W: Wg[n][tap*128 + c] bf16, K-contiguous per n
    int k = blk - (33 + 16384);    // 0..1151
    int n = t;                     // 0..255
    int tap = k >> 7, c = k & 127;
    float v = (c < 64) ? kern[((size_t)(tap*64 + c))*256 + n]
                       : rkern[((size_t)(tap*64 + (c-64)))*256 + n];
    Wg[(size_t)n*1152 + k] = f2bf(v);
  }
}

// ---------- gates: implicit-GEMM conv (M=128px row, N=256 gates, K=1152) + LSTM ----------
// FROZEN (R5 form, measured 235-237 us). Post-R5 model: at the forced
// 2-waves/SIMD operating point the wall ~= serialized pipe demands
// (MFMA 74 + LDS 61 + VALU 47 + L2 34 us); schedule variants all null.
__global__ __launch_bounds__(256, 2) void gates_kernel(
    const unsigned short* __restrict__ Xp,
    const unsigned short* __restrict__ Wg,
    const float* __restrict__ bias,
    const float* __restrict__ c0,
    float* __restrict__ c_out,
    unsigned short* __restrict__ h_bf){
  __shared__ unsigned short As[2][130*128];  // 2 x 33,280 B
  const int gid = blockIdx.x;
  const int swz = (gid & 7)*256 + (gid >> 3);
  const int b  = swz >> 7;
  const int y  = swz & 127;
  const int tid = threadIdx.x;
  const int l = tid & 63;
  const int wid = tid >> 6;                 // 0..3 (n-partition)
  const int l15 = l & 15, l4 = l >> 4;
  const int n0 = wid*16 + l15;              // channel-within-gate this lane owns

  const unsigned short* brow[4];
  #pragma unroll
  for (int g=0; g<4; ++g) brow[g] = Wg + (size_t)(g*64 + n0)*1152 + l4*8;

  f32x4 acc[8][4];                          // [m-frag][gate]
  #pragma unroll
  for (int mf=0;mf<8;++mf)
    #pragma unroll
    for (int g=0;g<4;++g) acc[mf][g] = (f32x4){0.f,0.f,0.f,0.f};

  auto stage = [&](int buf, int dyi){       // exactly 9 vmem insts per wave
    const unsigned short* gbase = Xp + ((size_t)((b*130 + y + dyi)*130))*128;
    unsigned short* lbase = &As[buf][0];
    #pragma unroll
    for (int it=0; it<8; ++it){             // 130*16 = 2080 chunks of 16B
      int q = it*256 + tid;
      int px = q >> 4, c = q & 15;
      int cs = c ^ (px & 7);
      gload_lds16(gbase + (size_t)px*128 + cs*8, lbase + (size_t)q*8);
    }
    if (l < 8){                             // per-wave tail: 8 chunks each
      int q = 2048 + wid*8 + l;
      int px = q >> 4, c = q & 15;
      int cs = c ^ (px & 7);
      gload_lds16(gbase + (size_t)px*128 + cs*8, lbase + (size_t)q*8);
    }
  };

  stage(0, 0);
  for (int dyi = 0; dyi < 3; ++dyi){
    if (dyi < 2){
      stage((dyi+1)&1, dyi+1);              // prefetch next strip (other buf)
      asm volatile("s_waitcnt vmcnt(9)" ::: "memory");   // current strip done;
    } else {                                             // prefetch in flight
      asm volatile("s_waitcnt vmcnt(0)" ::: "memory");
    }
    __builtin_amdgcn_sched_barrier(0);
    __builtin_amdgcn_s_barrier();           // all waves' strip data visible
    __builtin_amdgcn_sched_barrier(0);
    const unsigned short* asb = &As[dyi&1][0];
    #pragma unroll
    for (int dxi = 0; dxi < 3; ++dxi){
      const int tap = dyi*3 + dxi;
      #pragma unroll
      for (int ksc = 0; ksc < 2; ++ksc){    // two half-ksteps
        bf16x8 bfr[4][2];                   // 32 VGPR, serves 64 MFMAs
        #pragma unroll
        for (int g=0; g<4; ++g)
          #pragma unroll
          for (int k2=0; k2<2; ++k2)
            bfr[g][k2] = *(const bf16x8*)(brow[g] + tap*128 + (ksc*2+k2)*32);
        #pragma unroll
        for (int k2=0; k2<2; ++k2){
          const int cd = (ksc*2+k2)*4 + l4;
          #pragma unroll
          for (int mf=0; mf<8; ++mf){
            const int px = mf*16 + l15 + dxi;   // 0..129 in strip
            bf16x8 a = *(const bf16x8*)(asb + (size_t)px*128 + ((cd ^ (px & 7))*8));
            #pragma unroll
            for (int g=0;g<4;++g)
              acc[mf][g] = __builtin_amdgcn_mfma_f32_16x16x32_bf16(a, bfr[g][k2], acc[mf][g], 0,0,0);
          }
        }
      }
    }
    __builtin_amdgcn_sched_barrier(0);
    __builtin_amdgcn_s_barrier();           // reads done before buf reuse
    __builtin_amdgcn_sched_barrier(0);
  }
  // epilogue: all 4 gates of channel n0 live in the same lane/reg slot
  const float b0 = bias[n0], b1 = bias[64+n0], b2 = bias[128+n0], b3 = bias[192+n0];
  const size_t prow = (size_t)(b*128 + y)*128;
  #pragma unroll
  for (int mf=0;mf<8;++mf){
    #pragma unroll
    for (int r=0;r<4;++r){
      const int x = mf*16 + l4*4 + r;       // C/D row = (lane>>4)*4 + reg
      const size_t p = prow + x;
      const float zi_ = acc[mf][0][r] + b0;
      const float zf_ = acc[mf][1][r] + b1;
      const float zc_ = acc[mf][2][r] + b2;
      const float zo_ = acc[mf][3][r] + b3;
      const float iv = hsig(zi_), fv = hsig(zf_), ov = hsig(zo_);
      const float cv = fv*c0[p*64 + n0] + iv*tanh_fast(zc_);
      const float hv = ov*tanh_fast(cv);
      c_out[p*64 + n0] = cv;
      h_bf[p*64 + n0] = f2bf(hv);
    }
  }
}

// ---------- qkv: 5 channel contractions (R7 form, computed once) ----------
__global__ __launch_bounds__(256) void qkv_kernel(
    const unsigned short* __restrict__ h_bf, const float* __restrict__ m0,
    const float* __restrict__ sak,
    float* __restrict__ q_h, float* __restrict__ k_h, float* __restrict__ v_h,
    float* __restrict__ k_m, float* __restrict__ v_m){
  __shared__ float wS[320];
  for (int i = threadIdx.x; i < 320; i += 256) wS[i] = sak[i];
  __syncthreads();
  const int p = blockIdx.x*256 + threadIdx.x;
  const unsigned short* hp = h_bf + (size_t)p*64;
  const float* mp = m0 + (size_t)p*64;
  float a0=0,a1=0,a2=0,a3=0,a4=0;
  #pragma unroll
  for (int ch = 0; ch < 64; ch += 8){
    uint4 hu = *(const uint4*)(hp + ch);
    float4 ma = *(const float4*)(mp + ch);
    float4 mb = *(const float4*)(mp + ch + 4);
    float hv[8] = { bf2f(hu.x&0xffffu), bf2f(hu.x>>16), bf2f(hu.y&0xffffu), bf2f(hu.y>>16),
                    bf2f(hu.z&0xffffu), bf2f(hu.z>>16), bf2f(hu.w&0xffffu), bf2f(hu.w>>16) };
    float mv[8] = { ma.x,ma.y,ma.z,ma.w, mb.x,mb.y,mb.z,mb.w };
    #pragma unroll
    for (int jj=0;jj<8;++jj){
      const float* w = &wS[(ch+jj)*5];
      a0 = fmaf(hv[jj], w[0], a0);
      a1 = fmaf(hv[jj], w[1], a1);
      a2 = fmaf(hv[jj], w[2], a2);
      a3 = fmaf(mv[jj], w[3], a3);
      a4 = fmaf(mv[jj], w[4], a4);
    }
  }
  v_h[p]=a0; k_h[p]=a1; q_h[p]=a2; k_m[p]=a3; v_m[p]=a4;
}

// ---------- attention v3 (R7 form, measured good): LDS-staged K/V ----------
// 256 blocks (16b x 2type x 8rb) stage K,V coalesced into padded LDS once,
// 16 rows/block in 2 passes; thread owns 4 cols (float4 LDS reads); 32-lane
// shfl row softmax. LDS 143.6 KB -> 1 block/CU, one scheduling round.
__global__ __launch_bounds__(256) void attn_kernel(
    const float* __restrict__ q_h, const float* __restrict__ k_h, const float* __restrict__ v_h,
    const float* __restrict__ k_m, const float* __restrict__ v_m,
    float* __restrict__ z_h, float* __restrict__ z_m){
  __shared__ float Kl[128][132];
  __shared__ float Vl[128][132];
  __shared__ float q2[8][132];
  __shared__ float al[8][132];
  const int bid = blockIdx.x;              // 16b x 2type x 8rb
  const int b = bid >> 4;
  const int type = (bid >> 3) & 1;
  const int rb = bid & 7;
  const float* K = (type ? k_m : k_h) + (size_t)b*16384;
  const float* V = (type ? v_m : v_h) + (size_t)b*16384;
  const float* Q = q_h + (size_t)b*16384;
  float* Z = (type ? z_m : z_h) + (size_t)b*16384;
  const int t = threadIdx.x;
  const int jq = t & 31;                   // col quad: j = jq*4
  const int r8 = t >> 5;                   // row within pass: 0..7

  // stage K,V coalesced (reg-staged; padded pitch 132)
  for (int base = 0; base < 16384; base += 1024){
    const int idx = base + t*4;
    const int w = idx >> 7, j = idx & 127;
    const float4 kv = *(const float4*)(K + idx);
    const float4 vv = *(const float4*)(V + idx);
    *(float4*)&Kl[w][j] = kv;
    *(float4*)&Vl[w][j] = vv;
  }

  for (int p = 0; p < 2; ++p){
    __syncthreads();                       // staging done / prev pass done
    for (int idx = t; idx < 1024; idx += 256)
      q2[idx>>7][idx&127] = Q[(rb*16 + p*8 + (idx>>7))*128 + (idx&127)];
    __syncthreads();
    const int i = rb*16 + p*8 + r8;
    float s0=0.f,s1=0.f,s2=0.f,s3=0.f;
    #pragma unroll 8
    for (int w=0; w<128; ++w){
      const float qv = q2[r8][w];
      const float4 kv = *(const float4*)&Kl[w][jq*4];
      s0 = fmaf(qv, kv.x, s0); s1 = fmaf(qv, kv.y, s1);
      s2 = fmaf(qv, kv.z, s2); s3 = fmaf(qv, kv.w, s3);
    }
    float mx = fmaxf(fmaxf(s0,s1), fmaxf(s2,s3));
    #pragma unroll
    for (int o=1;o<32;o<<=1) mx = fmaxf(mx, __shfl_xor(mx, o));
    const float p0 = __expf(s0-mx), p1 = __expf(s1-mx);
    const float p2 = __expf(s2-mx), p3 = __expf(s3-mx);
    float sm = (p0+p1)+(p2+p3);
    #pragma unroll
    for (int o=1;o<32;o<<=1) sm += __shfl_xor(sm, o);
    const float inv = 1.f/sm;
    *(float4*)&al[r8][jq*4] = make_float4(p0*inv, p1*inv, p2*inv, p3*inv);
    __syncthreads();
    float z0=0.f,z1=0.f,z2=0.f,z3=0.f;
    #pragma unroll 8
    for (int w=0; w<128; ++w){
      const float av = al[r8][w];
      const float4 vv = *(const float4*)&Vl[w][jq*4];
      z0 = fmaf(av, vv.x, z0); z1 = fmaf(av, vv.y, z1);
      z2 = fmaf(av, vv.z, z2); z3 = fmaf(av, vv.w, z3);
    }
    *(float4*)(Z + (size_t)i*128 + jq*4) = make_float4(z0,z1,z2,z3);
  }
}

// ---------- FUSED zconv + depthwise/SAM final ----------
__global__ __launch_bounds__(512) void final_fused(
    const float* __restrict__ z_h, const float* __restrict__ z_m,
    const float* __restrict__ kz,
    const unsigned short* __restrict__ h_bf,
    const float* __restrict__ m0, const float* __restrict__ dwk,
    const float* __restrict__ sab,
    float* __restrict__ hhat, float* __restrict__ m_t){
  __shared__ unsigned short zi[4][128][64];   // 64 KB
  const int f = threadIdx.x & 63;
  const int g = threadIdx.x >> 6;             // 0..7
  const int blk = blockIdx.x;                 // 16 b x 64 ytiles (2 rows)
  const int b = blk >> 6;
  const int y0 = (blk & 63) * 2;

  // ---- phase 1: zi rows y0-1..y0+2 -> LDS ----
  {
    const int ry = g >> 1;                    // 0..3 (which zi row)
    const int xh = g & 1;                     // x half
    const int yy = y0 - 1 + ry;
    const int x0 = xh * 64;
    if ((unsigned)yy >= 128u){
      for (int i=0;i<64;++i) zi[ry][x0+i][f] = 0;
    } else {
      float w0[9], w1[9];
      #pragma unroll
      for (int tap=0; tap<9; ++tap){
        w0[tap] = kz[tap*128 + f];
        w1[tap] = kz[tap*128 + 64 + f];
      }
      const float* zhr = z_h + (size_t)(b*128 + yy)*128;
      const float* zmr = z_m + (size_t)(b*128 + yy)*128;
      const bool ym = (yy > 0), yp = (yy < 127);
      float az[3][3], am[3][3];               // [col: x-1,x,x+1][row dy 0..2]
      auto ldc = [&](int x, float (&Z)[3], float (&M)[3]){
        if ((unsigned)x < 128u){
          Z[0] = ym ? zhr[x-128] : 0.f;  M[0] = ym ? zmr[x-128] : 0.f;
          Z[1] = zhr[x];                 M[1] = zmr[x];
          Z[2] = yp ? zhr[x+128] : 0.f;  M[2] = yp ? zmr[x+128] : 0.f;
        } else { Z[0]=Z[1]=Z[2]=0.f; M[0]=M[1]=M[2]=0.f; }
      };
      ldc(x0-1, az[0], am[0]);
      ldc(x0,   az[1], am[1]);
      for (int i=0; i<64; ++i){
        const int x = x0 + i;
        ldc(x+1, az[2], am[2]);
        float acc = 0.f;
        #pragma unroll
        for (int tap=0; tap<9; ++tap){
          const int dy = tap/3, dx = tap%3;
          acc = fmaf(az[dx][dy], w0[tap], acc);
          acc = fmaf(am[dx][dy], w1[tap], acc);
        }
        zi[ry][x][f] = f2bf(acc);
        #pragma unroll
        for (int k=0;k<3;++k){
          az[0][k]=az[1][k]; az[1][k]=az[2][k];
          am[0][k]=am[1][k]; am[1][k]=am[2][k];
        }
      }
    }
  }
  __syncthreads();

  // ---- phase 2: depthwise convs + SAM gates + elementwise ----
  const int r2 = g >> 2;                      // output row within tile (0/1)
  const int xq = g & 3;                       // x quarter
  const int y = y0 + r2;
  const size_t rb = (size_t)(b*128 + y)*128;
  float wv[9][6];
  #pragma unroll
  for (int tap=0;tap<9;++tap)
    #pragma unroll
    for (int jj=0;jj<6;++jj) wv[tap][jj] = dwk[(tap*64 + f)*6 + jj];
  const float bi = sab[f], bg = sab[64+f], bo = sab[128+f];
  const bool ym = (y > 0), yp = (y < 127);
  float vz[3][3], vh[3][3];                   // [col: x-1,x,x+1][row dy 0..2]
  auto ldc2 = [&](int x, float (&Z)[3], float (&H)[3]){
    if ((unsigned)x < 128u){
      const size_t base = (rb + x)*64 + f;
      H[0] = ym ? bf2f(h_bf[base - 8192]) : 0.f;
      H[1] = bf2f(h_bf[base]);
      H[2] = yp ? bf2f(h_bf[base + 8192]) : 0.f;
      Z[0] = bf2f(zi[r2  ][x][f]);            // zi row y-1 (zero-filled if OOR)
      Z[1] = bf2f(zi[r2+1][x][f]);            // zi row y
      Z[2] = bf2f(zi[r2+2][x][f]);            // zi row y+1
    } else { Z[0]=Z[1]=Z[2]=0.f; H[0]=H[1]=H[2]=0.f; }
  };
  const int x0 = xq*32;
  ldc2(x0-1, vz[0], vh[0]);
  ldc2(x0,   vz[1], vh[1]);
  for (int i=0; i<32; ++i){
    const int x = x0 + i;
    ldc2(x+1, vz[2], vh[2]);
    float si=0.f, sg=0.f, so=0.f;
    #pragma unroll
    for (int tap=0;tap<9;++tap){
      const int dy = tap/3, dx = tap%3;
      const float zv = vz[dx][dy], hv = vh[dx][dy];
      si = fmaf(zv, wv[tap][0], si); si = fmaf(hv, wv[tap][1], si);
      sg = fmaf(zv, wv[tap][2], sg); sg = fmaf(hv, wv[tap][3], sg);
      so = fmaf(zv, wv[tap][4], so); so = fmaf(hv, wv[tap][5], so);
    }
    const size_t p = rb + x;
    const float i2 = 1.f/(1.f+__expf(-(si+bi)));
    const float gg = tanh_fast(sg+bg);
    const float o2 = 1.f/(1.f+__expf(-(so+bo)));
    const float mv = m0[p*64+f];
    const float mt = (1.f-i2)*mv + i2*gg;
    hhat[p*64+f] = mt*o2;
    m_t[p*64+f]  = mt;
    #pragma unroll
    for (int k=0;k<3;++k){
      vz[0][k]=vz[1][k]; vz[1][k]=vz[2][k];
      vh[0][k]=vh[1][k]; vh[1][k]=vh[2][k];
    }
  }
}

extern "C" void kernel_launch(void* const* d_in, const int* in_sizes, int n_in,
                              void* d_out, int out_size, void* d_ws, size_t ws_size,
                              hipStream_t stream){
  const float* inputs = (const float*)d_in[0];
  const float* h0p    = (const float*)d_in[1];
  const float* c0p    = (const float*)d_in[2];
  const float* m0p    = (const float*)d_in[3];
  const float* kern   = (const float*)d_in[4];
  const float* rkern  = (const float*)d_in[5];
  const float* biasp  = (const float*)d_in[6];
  const float* sakp   = (const float*)d_in[7];
  const float* kzp    = (const float*)d_in[8];
  const float* dwkp   = (const float*)d_in[9];
  const float* sabp   = (const float*)d_in[10];
  float* out = (float*)d_out;
  char* ws = (char*)d_ws;

  constexpr size_t SZ_XP  = (size_t)16*130*130*128*2;  // 69,222,400
  constexpr size_t SZ_WG  = (size_t)256*1152*2;        //    589,824
  constexpr size_t SZ_HBF = (size_t)NPIX*64*2;         // 33,554,432
  constexpr size_t SZA    = (size_t)NPIX*4;            //  1,048,576
  constexpr size_t OFF_XP  = 0;
  constexpr size_t OFF_WG  = OFF_XP + SZ_XP;
  constexpr size_t OFF_HBF = OFF_WG + SZ_WG;
  constexpr size_t OFF_Q   = OFF_HBF + SZ_HBF;
  constexpr size_t OFF_KH  = OFF_Q  + SZA;
  constexpr size_t OFF_VH  = OFF_KH + SZA;
  constexpr size_t OFF_KM  = OFF_VH + SZA;
  constexpr size_t OFF_VM  = OFF_KM + SZA;
  constexpr size_t OFF_ZH  = OFF_VM + SZA;
  constexpr size_t OFF_ZM  = OFF_ZH + SZA;

  unsigned short* Xp  = (unsigned short*)(ws + OFF_XP);
  unsigned short* Wg  = (unsigned short*)(ws + OFF_WG);
  unsigned short* Hbf = (unsigned short*)(ws + OFF_HBF);
  float* Qh = (float*)(ws + OFF_Q);
  float* Kh = (float*)(ws + OFF_KH);
  float* Vh = (float*)(ws + OFF_VH);
  float* Km = (float*)(ws + OFF_KM);
  float* Vm = (float*)(ws + OFF_VM);
  float* Zh = (float*)(ws + OFF_ZH);
  float* Zm = (float*)(ws + OFF_ZM);

  prep_all<<<33 + 16384 + 1152, 256, 0, stream>>>(inputs, h0p, kern, rkern, Xp, Wg);
  gates_kernel<<<2048, 256, 0, stream>>>(Xp, Wg, biasp, c0p,
                                         out + (size_t)NPIX*64, Hbf);
  qkv_kernel<<<NPIX/256, 256, 0, stream>>>(Hbf, m0p, sakp, Qh, Kh, Vh, Km, Vm);
  attn_kernel<<<256, 256, 0, stream>>>(Qh, Kh, Vh, Km, Vm, Zh, Zm);
  final_fused<<<1024, 512, 0, stream>>>(Zh, Zm, kzp, Hbf, m0p, dwkp, sabp,
                                        out, out + 2*(size_t)NPIX*64);
}